// Round 3
// baseline (746.145 us; speedup 1.0000x reference)
//
#include <hip/hip_runtime.h>
#include <math.h>

#define D      256
#define K      16384
#define NPTS   8192
#define DELTA  0.2f

// d_out layout (all f32): zq[8,256,32,32] | indices[8192] | bit[8,32,32,256] | loss[1]
#define O_IDX  2097152
#define O_BIT  2105344
#define O_LOSS 4202496

typedef __attribute__((ext_vector_type(8))) short bf16x8;
typedef __attribute__((ext_vector_type(4))) float f32x4;

__device__ __forceinline__ unsigned f2s(float f) {
    unsigned u = __float_as_uint(f);
    return (u & 0x80000000u) ? ~u : (u | 0x80000000u);
}
__device__ __forceinline__ float s2f(unsigned s) {
    return __uint_as_float((s & 0x80000000u) ? (s & 0x7fffffffu) : ~s);
}
__device__ __forceinline__ unsigned short f2bf(float f) {  // round-to-nearest-even
    unsigned u = __float_as_uint(f);
    u += 0x7fffu + ((u >> 16) & 1u);
    return (unsigned short)(u >> 16);
}
__device__ __forceinline__ void gl2lds16(const unsigned short* g, unsigned short* l) {
    __builtin_amdgcn_global_load_lds(
        (const __attribute__((address_space(1))) void*)g,
        (__attribute__((address_space(3))) void*)l, 16, 0, 0);
}

// ---- normalize codebook rows (fp32 + bf16) + zero argmax state ----
__global__ __launch_bounds__(256) void normalize_rows(const float* __restrict__ E,
                                                      float* __restrict__ ew32,
                                                      unsigned short* __restrict__ ewb,
                                                      unsigned* __restrict__ gmax,
                                                      unsigned long long* __restrict__ keys) {
    const int row = blockIdx.x;
    const int tid = threadIdx.x;
    if (row < 32) {
        gmax[row * 256 + tid] = 0u;
        keys[row * 256 + tid] = 0ull;
    }
    const float x = E[(size_t)row * D + tid];
    float s = x * x;
    #pragma unroll
    for (int o = 32; o > 0; o >>= 1) s += __shfl_xor(s, o);
    __shared__ float ws_[4];
    if ((tid & 63) == 0) ws_[tid >> 6] = s;
    __syncthreads();
    const float tot = ws_[0] + ws_[1] + ws_[2] + ws_[3];
    const float v = x / fmaxf(sqrtf(tot), 1e-12f);
    ew32[(size_t)row * D + tid] = v;
    ewb [(size_t)row * D + tid] = f2bf(v);
}

// ---- z [8,256,1024] -> zf [8192,256] (fp32 + bf16) ----
__global__ __launch_bounds__(256) void transpose_z(const float* __restrict__ z,
                                                   float* __restrict__ zf32,
                                                   unsigned short* __restrict__ zfb) {
    const int bi = blockIdx.x, tid = threadIdx.x;
    const int b = bi >> 4, hw0 = (bi & 15) * 64;
    __shared__ float t[64][65];
    for (int dc = 0; dc < D; dc += 64) {
        #pragma unroll
        for (int it = 0; it < 16; ++it) {
            const int idx = it * 256 + tid;
            const int dl = idx >> 6, hw = idx & 63;
            t[dl][hw] = z[(size_t)(b * 256 + dc + dl) * 1024 + hw0 + hw];
        }
        __syncthreads();
        #pragma unroll
        for (int it = 0; it < 16; ++it) {
            const int idx = it * 256 + tid;
            const int pl = idx >> 6, dl = idx & 63;
            const float v = t[dl][pl];
            const size_t o = (size_t)(b * 1024 + hw0 + pl) * D + dc + dl;
            zf32[o] = v;
            zfb[o]  = f2bf(v);
        }
        __syncthreads();
    }
}

// exact fp32 rescore: deterministic summation order
__device__ __attribute__((noinline)) void rescore(const float* __restrict__ zf32,
                                                  const float* __restrict__ ew32,
                                                  int gp, int gc,
                                                  unsigned long long* __restrict__ keys) {
    const float4* ap = (const float4*)(zf32 + (size_t)gp * D);
    const float4* bp = (const float4*)(ew32 + (size_t)gc * D);
    float s = 0.f;
    #pragma unroll 4
    for (int i = 0; i < 64; ++i) {
        const float4 a = ap[i], b = bp[i];
        s = fmaf(a.x, b.x, fmaf(a.y, b.y, fmaf(a.z, b.z, fmaf(a.w, b.w, s))));
    }
    const unsigned long long key =
        ((unsigned long long)f2s(s) << 32) | (unsigned)(16383 - gc);
    atomicMax(keys + gp, key);
}

// ---- bf16 MFMA scores + per-point max + exact rescore of near-max candidates ----
// grid = (K/128, NPTS/128), block = 256; tile 128 points x 128 codes
__global__ __launch_bounds__(256) void score_mfma(const unsigned short* __restrict__ zfb,
                                                  const unsigned short* __restrict__ ewb,
                                                  const float* __restrict__ zf32,
                                                  const float* __restrict__ ew32,
                                                  unsigned* __restrict__ gmax,
                                                  unsigned long long* __restrict__ keys) {
    __shared__ __align__(16) unsigned short za[128 * 32];  // 8 KB: [row][32 shorts]
    __shared__ __align__(16) unsigned short eb[128 * 32];  // 8 KB
    __shared__ unsigned smaxu[128];
    __shared__ float thr[128];

    const int tid  = threadIdx.x;
    const int lane = tid & 63, wave = tid >> 6;
    const int quad = lane >> 4, col = lane & 15;
    const int wm   = wave >> 1, wn = wave & 1;
    const int n0   = blockIdx.x * 128;
    const int m0   = blockIdx.y * 128;

    if (tid < 128) smaxu[tid] = 0u;

    // staging source: lane -> (row = wave*32 + lane/4, 16B chunk = lane%4)
    const int srow = wave * 32 + (lane >> 2);
    const int schk = (lane & 3) * 8;
    const unsigned short* gA = zfb + (size_t)(m0 + srow) * D + schk;
    const unsigned short* gB = ewb + (size_t)(n0 + srow) * D + schk;
    unsigned short* lA = &za[(wave * 32) * 32];   // wave-uniform LDS base
    unsigned short* lB = &eb[(wave * 32) * 32];

    f32x4 acc[4][4];
    #pragma unroll
    for (int i = 0; i < 4; ++i)
        #pragma unroll
        for (int j = 0; j < 4; ++j)
            acc[i][j] = (f32x4){0.f, 0.f, 0.f, 0.f};

    for (int dc = 0; dc < D; dc += 32) {
        __syncthreads();
        gl2lds16(gA + dc,           lA);
        gl2lds16(gA + dc + 16 * D,  lA + 16 * 32);
        gl2lds16(gB + dc,           lB);
        gl2lds16(gB + dc + 16 * D,  lB + 16 * 32);
        __syncthreads();
        bf16x8 af[4], bfr[4];
        #pragma unroll
        for (int mt = 0; mt < 4; ++mt)
            af[mt] = *(const bf16x8*)&za[(wm * 64 + mt * 16 + col) * 32 + quad * 8];
        #pragma unroll
        for (int nt = 0; nt < 4; ++nt)
            bfr[nt] = *(const bf16x8*)&eb[(wn * 64 + nt * 16 + col) * 32 + quad * 8];
        #pragma unroll
        for (int mt = 0; mt < 4; ++mt)
            #pragma unroll
            for (int nt = 0; nt < 4; ++nt)
                acc[mt][nt] = __builtin_amdgcn_mfma_f32_16x16x32_bf16(af[mt], bfr[nt],
                                                                      acc[mt][nt], 0, 0, 0);
    }

    // per-point local max over this block's 128-code slice
    float pm[4][4];
    #pragma unroll
    for (int mt = 0; mt < 4; ++mt)
        #pragma unroll
        for (int r = 0; r < 4; ++r)
            pm[mt][r] = fmaxf(fmaxf(acc[mt][0][r], acc[mt][1][r]),
                              fmaxf(acc[mt][2][r], acc[mt][3][r]));
    #pragma unroll
    for (int off = 1; off < 16; off <<= 1)
        #pragma unroll
        for (int mt = 0; mt < 4; ++mt)
            #pragma unroll
            for (int r = 0; r < 4; ++r)
                pm[mt][r] = fmaxf(pm[mt][r], __shfl_xor(pm[mt][r], off));
    if (col == 0) {
        #pragma unroll
        for (int mt = 0; mt < 4; ++mt)
            #pragma unroll
            for (int r = 0; r < 4; ++r)
                atomicMax(&smaxu[wm * 64 + mt * 16 + quad * 4 + r], f2s(pm[mt][r]));
    }
    __syncthreads();
    if (tid < 128) {
        const unsigned mine = smaxu[tid];
        const unsigned old  = atomicMax(&gmax[m0 + tid], mine);
        thr[tid] = s2f(old > mine ? old : mine) - DELTA;
    }
    __syncthreads();

    #pragma unroll
    for (int mt = 0; mt < 4; ++mt) {
        #pragma unroll
        for (int r = 0; r < 4; ++r) {
            const int p    = wm * 64 + mt * 16 + quad * 4 + r;
            const float tp = thr[p];
            #pragma unroll
            for (int nt = 0; nt < 4; ++nt) {
                if (acc[mt][nt][r] >= tp)
                    rescore(zf32, ew32, m0 + p, n0 + wn * 64 + nt * 16 + col, keys);
            }
        }
    }
}

// ---- gather + outputs ----
__global__ __launch_bounds__(256) void finalize(const float* __restrict__ ew32,
                                                const unsigned long long* __restrict__ keys,
                                                float* __restrict__ out) {
    const int n = blockIdx.x, tid = threadIdx.x;
    const unsigned long long key = keys[n];
    const int idx = 16383 - (int)(unsigned)(key & 0xffffffffull);
    const float v = ew32[(size_t)idx * D + tid];
    const int b = n >> 10, off = n & 1023;
    out[(size_t)(b * D + tid) * 1024 + off] = v;
    const float S = 5.65685424949238019520675489683895f;  // sqrt(32)
    out[O_BIT + (size_t)n * D + tid] = (float)((int)(v * S) + 4);
    if (tid == 0) out[O_IDX + n] = (float)idx;
    if (n == 0 && tid == 0) out[O_LOSS] = 0.0f;
}

extern "C" void kernel_launch(void* const* d_in, const int* in_sizes, int n_in,
                              void* d_out, int out_size, void* d_ws, size_t ws_size,
                              hipStream_t stream) {
    const float* z = (const float*)d_in[0];
    const float* E = (const float*)d_in[1];
    float* out = (float*)d_out;

    float* ew32          = (float*)d_ws;                                   // 16 MB
    float* zf32          = ew32 + (size_t)K * D;                           //  8 MB
    unsigned short* ewb  = (unsigned short*)(zf32 + (size_t)NPTS * D);     //  8 MB
    unsigned short* zfb  = ewb + (size_t)K * D;                            //  4 MB
    unsigned long long* keys = (unsigned long long*)(zfb + (size_t)NPTS * D); // 64 KB
    unsigned* gmax       = (unsigned*)(keys + NPTS);                       // 32 KB

    normalize_rows<<<K, 256, 0, stream>>>(E, ew32, ewb, gmax, keys);
    transpose_z<<<128, 256, 0, stream>>>(z, zf32, zfb);

    dim3 gmain(K / 128, NPTS / 128);
    score_mfma<<<gmain, 256, 0, stream>>>(zfb, ewb, zf32, ew32, gmax, keys);

    finalize<<<NPTS, 256, 0, stream>>>(ew32, keys, out);
}